// Round 3
// baseline (263.373 us; speedup 1.0000x reference)
//
#include <hip/hip_runtime.h>
#include <hip/hip_bf16.h>
#include <cstdint>

// Problem constants
#define B_DIM 16384
#define DX 256
#define DH 512
#define DS 128
#define DT 128
#define KDIM 1024   // DX+DH+DS+DT
#define NDIM 2048   // 4*DH
#define HOUT 512

#define NT 32       // K-tiles of BK=32
#define SLOT 4096   // ushorts per 8KB LDS slot (128 rows x 32 k x 2B)

typedef __attribute__((ext_vector_type(8))) short short8;
typedef __attribute__((ext_vector_type(4))) float floatx4;

union bf16x8 {
  short8 v;
  __hip_bfloat16 b[8];
};

__device__ __forceinline__ float fast_sigmoid(float x) {
  return 1.f / (1.f + __expf(-x));
}
__device__ __forceinline__ float fast_tanh(float x) {
  float e = __expf(-2.f * x);
  return (1.f - e) / (1.f + e);
}

// ===========================================================================
// A layout: row-major bf16 concat [B][1024]  (k: 0..255 x, 256..767 h,
//   768..895 s, 896..1023 t).
// W layout: row-major bf16 [pcol][1024], pcol = nblk*128 + wn*64 + g*16 + hl
//   <-> orig col = g*512 + (nblk*32 + wn*16 + hl)   (g: 0=i,1=f,2=o,3=c~)
//   so a wave's 64-col tile = 4 gates x 16 hh -> register epilogue.
// GEMM stages via global_load_lds with PER-LANE pre-swizzled global source
// addresses (LDS dest stays linear): LDS slot holds [row][32k]; the 16B
// k-chunk at linear position qlin contains global chunk qlin ^ ((row>>1)&3).
// Fragment reads apply the same XOR -> 0 bank conflicts (verified round 2).
// ===========================================================================

__global__ __launch_bounds__(256) void pack_AW(
    const float* __restrict__ x, const float* __restrict__ h,
    const float* __restrict__ s, const float* __restrict__ t,
    const float* __restrict__ Wx, const float* __restrict__ Wh,
    const float* __restrict__ Ws, const float* __restrict__ Wt,
    __hip_bfloat16* __restrict__ Ap, __hip_bfloat16* __restrict__ Wp) {
  const int bid = blockIdx.x;
  if (bid < B_DIM * KDIM / 8 / 256) {
    // ---- pack_A: pure streaming fp32 -> bf16, row-major concat ----
    int tid = bid * 256 + threadIdx.x;   // 0 .. B_DIM*KDIM/8-1
    int r = tid >> 7;                    // row 0..16383
    int k = (tid & 127) * 8;             // 0..1016
    const float* p;
    if (k < 768) {
      p = (k < 256) ? (x + (size_t)r * DX + k) : (h + (size_t)r * DH + (k - 256));
    } else {
      p = (k < 896) ? (s + (size_t)r * DS + (k - 768)) : (t + (size_t)r * DT + (k - 896));
    }
    floatx4 v0 = *(const floatx4*)p;
    floatx4 v1 = *(const floatx4*)(p + 4);
    bf16x8 o;
#pragma unroll
    for (int j = 0; j < 4; ++j) {
      o.b[j]     = __float2bfloat16(v0[j]);
      o.b[4 + j] = __float2bfloat16(v1[j]);
    }
    *(short8*)(Ap + (size_t)tid * 8) = o.v;
  } else {
    // ---- pack_W: gather to row-major [pcol][1024] ----
    int tid = (bid - B_DIM * KDIM / 8 / 256) * 256 + threadIdx.x;  // 0..NDIM*KDIM/8-1
    int pcol = tid >> 7;            // packed col 0..2047
    int k0 = (tid & 127) * 8;       // 0..1016
    int nblk = pcol >> 7, r7 = pcol & 127;
    int wn = r7 >> 6, g = (r7 >> 4) & 3, hl = r7 & 15;
    int col = g * 512 + nblk * 32 + wn * 16 + hl;
    const float* src; int kl;
    if (k0 < 256)      { src = Wx; kl = k0; }
    else if (k0 < 768) { src = Wh; kl = k0 - 256; }
    else if (k0 < 896) { src = Ws; kl = k0 - 768; }
    else               { src = Wt; kl = k0 - 896; }
    bf16x8 o;
#pragma unroll
    for (int rr = 0; rr < 8; ++rr)
      o.b[rr] = __float2bfloat16(src[(size_t)(kl + rr) * NDIM + col]);
    *(short8*)(Wp + (size_t)tid * 8) = o.v;  // Wp[pcol][k0..k0+7]
  }
}

// ---------------------------------------------------------------------------
// Round-0 geometry (128x128 tile, 2x2 waves, 4x4 MFMA acc/wave, BK=32,
// 256 threads, ~3 blocks/CU TLP) + round-2's proven pieces:
//   T2 XOR swizzle (0 bank conflicts), T1 XCD swizzle, counted-vmcnt ring.
// 3-slot LDS ring (48KB), ONE raw s_barrier per tile preceded by
// s_waitcnt vmcnt(4): tile t+1 validated, tile t+2's 4 loads stay in flight.
// No __syncthreads -> no vmcnt(0)/lgkmcnt(0) drain in the K-loop.
// ---------------------------------------------------------------------------
#define GLD(src, dst)                                              \
  __builtin_amdgcn_global_load_lds(                                \
      (const __attribute__((address_space(1))) void*)(src),        \
      (__attribute__((address_space(3))) void*)(dst), 16, 0, 0)

__global__ __launch_bounds__(256, 3) void lstm_gemm(
    const __hip_bfloat16* __restrict__ Ap, const __hip_bfloat16* __restrict__ Wp,
    const float* __restrict__ bh, const float* __restrict__ c_in,
    float* __restrict__ out) {
  __shared__ unsigned short As[3 * SLOT];  // 24 KB
  __shared__ unsigned short Bs[3 * SLOT];  // 24 KB

  const int tid = threadIdx.x;
  const int lane = tid & 63;
  const int wid = tid >> 6;      // 0..3
  const int wm = wid & 1;        // row half (64 rows)
  const int wn = wid >> 1;       // col half (64 packed cols)
  const int q = lane >> 4;
  const int fr = lane & 15;

  // XCD-aware bijective swizzle (2048 blocks, 2048%8==0): each XCD gets a
  // contiguous band of wg -> blocks sharing an A-panel land on one XCD's L2.
  const int bid = blockIdx.x;
  const int wg = (bid & 7) * 256 + (bid >> 3);
  const int mb = wg >> 4;        // 0..127
  const int nblk = wg & 15;      // 0..15
  const int m0 = mb * 128;

  // Fragment read offsets (ushort idx within slot), XOR-swizzled
  int aOff[4], bOff[4];
#pragma unroll
  for (int m = 0; m < 4; ++m) {
    int row = wm * 64 + m * 16 + fr;
    aOff[m] = row * 32 + (q ^ ((row >> 1) & 3)) * 8;
  }
#pragma unroll
  for (int n = 0; n < 4; ++n) {
    int colc = wn * 64 + n * 16 + fr;
    bOff[n] = colc * 32 + (q ^ ((colc >> 1) & 3)) * 8;
  }

  // Per-lane pre-swizzled global source addrs. Chunk c = wid*2+j (1KB each)
  // covers rows c*16..c*16+15; lane -> row c*16 + lane/4, 16B k-chunk lane&3.
  const int c0 = wid * 2, c1 = c0 + 1;
  const int r0 = c0 * 16 + (lane >> 2), r1 = c1 * 16 + (lane >> 2);
  const int ql = lane & 3;
  const int q0 = ql ^ ((r0 >> 1) & 3);
  const int q1 = ql ^ ((r1 >> 1) & 3);
  const __hip_bfloat16* aP0 = Ap + (size_t)(m0 + r0) * KDIM + q0 * 8;
  const __hip_bfloat16* aP1 = Ap + (size_t)(m0 + r1) * KDIM + q1 * 8;
  const __hip_bfloat16* bP0 = Wp + (size_t)(nblk * 128 + r0) * KDIM + q0 * 8;
  const __hip_bfloat16* bP1 = Wp + (size_t)(nblk * 128 + r1) * KDIM + q1 * 8;
  const int dA0 = c0 * 512, dA1 = c1 * 512;   // LDS dest bases (ushort idx)

  floatx4 acc[4][4];
#pragma unroll
  for (int i = 0; i < 4; ++i)
#pragma unroll
    for (int j = 0; j < 4; ++j) acc[i][j] = (floatx4)0.f;

  // ---- Prologue: stage tiles 0 (slot 0) and 1 (slot 1); 8 GLDs/thread ----
  GLD(aP0,      &As[dA0]);        GLD(aP1,      &As[dA1]);
  GLD(bP0,      &Bs[dA0]);        GLD(bP1,      &Bs[dA1]);
  GLD(aP0 + 32, &As[SLOT + dA0]); GLD(aP1 + 32, &As[SLOT + dA1]);
  GLD(bP0 + 32, &Bs[SLOT + dA0]); GLD(bP1 + 32, &Bs[SLOT + dA1]);
  asm volatile("s_waitcnt vmcnt(4)\n\ts_barrier" ::: "memory");  // tile 0 landed

  int sR = 0;          // read slot offset (tile t)
  int sS = 2 * SLOT;   // stage slot offset (tile t+2)

  for (int t = 0; t < NT; ++t) {
    // Tail clamp: re-stage tile 31's bytes into an unused slot (benign),
    // keeps the 4-GLD/tile vmcnt accounting uniform.
    const int ts = (t + 2 < NT) ? (t + 2) : (NT - 1);
    const int kO = ts * 32;

    // Stage early (issue VMEM first), compute under it.
    GLD(aP0 + kO, &As[sS + dA0]);
    GLD(aP1 + kO, &As[sS + dA1]);
    GLD(bP0 + kO, &Bs[sS + dA0]);
    GLD(bP1 + kO, &Bs[sS + dA1]);

    short8 af[4], bf[4];
#pragma unroll
    for (int i = 0; i < 4; ++i) af[i] = *(const short8*)&As[sR + aOff[i]];
#pragma unroll
    for (int i = 0; i < 4; ++i) bf[i] = *(const short8*)&Bs[sR + bOff[i]];

    __builtin_amdgcn_s_setprio(1);
#pragma unroll
    for (int mi = 0; mi < 4; ++mi)
#pragma unroll
      for (int ni = 0; ni < 4; ++ni)
        acc[mi][ni] = __builtin_amdgcn_mfma_f32_16x16x32_bf16(
            af[mi], bf[ni], acc[mi][ni], 0, 0, 0);
    __builtin_amdgcn_s_setprio(0);

    // Validate tile t+1 (drain its 4 loads), keep tile t+2's 4 in flight.
    asm volatile("s_waitcnt vmcnt(4)\n\ts_barrier" ::: "memory");

    sR = (sR == 2 * SLOT) ? 0 : sR + SLOT;
    sS = (sS == 2 * SLOT) ? 0 : sS + SLOT;
  }

  // ---- In-register epilogue ----
  // acc[mi][g]: rows m0 + wm*64 + mi*16 + q*4 + r, gate g of hidden hh.
  const int hh = nblk * 32 + wn * 16 + fr;
  float bias[4];
#pragma unroll
  for (int g = 0; g < 4; ++g) bias[g] = bh[g * 512 + hh];

#pragma unroll
  for (int mi = 0; mi < 4; ++mi) {
#pragma unroll
    for (int r = 0; r < 4; ++r) {
      const size_t grow = (size_t)(m0 + wm * 64 + mi * 16 + q * 4 + r);
      const float pi = acc[mi][0][r] + bias[0];
      const float pf = acc[mi][1][r] + bias[1];
      const float po = acc[mi][2][r] + bias[2];
      const float pc = acc[mi][3][r] + bias[3];
      const float ig = fast_sigmoid(pi);
      const float fg = fast_sigmoid(pf);
      const float og = fast_sigmoid(po);
      const float cg = fast_tanh(pc);
      const float cc = fg * c_in[grow * HOUT + hh] + ig * cg;
      out[grow * HOUT + hh] = fast_tanh(og * cc);  // faithful: tanh(o*c_new)
      out[(size_t)B_DIM * HOUT + grow * HOUT + hh] = cc;
    }
  }
}

// ---------------------------------------------------------------------------
extern "C" void kernel_launch(void* const* d_in, const int* in_sizes, int n_in,
                              void* d_out, int out_size, void* d_ws, size_t ws_size,
                              hipStream_t stream) {
  const float* x  = (const float*)d_in[0];
  const float* h  = (const float*)d_in[1];
  const float* c  = (const float*)d_in[2];
  const float* sp = (const float*)d_in[3];
  const float* tp = (const float*)d_in[4];
  const float* Wx = (const float*)d_in[5];
  const float* Wh = (const float*)d_in[6];
  const float* bh = (const float*)d_in[7];
  const float* Ws = (const float*)d_in[8];
  const float* Wt = (const float*)d_in[9];
  float* out = (float*)d_out;

  __hip_bfloat16* Ap = (__hip_bfloat16*)d_ws;                                     // 32 MB
  __hip_bfloat16* Wp = (__hip_bfloat16*)((char*)d_ws + (size_t)B_DIM * KDIM * 2); // 4 MB

  const int nblk_A = B_DIM * KDIM / 8 / 256;   // 8192
  const int nblk_W = NDIM * KDIM / 8 / 256;    // 1024
  pack_AW<<<dim3(nblk_A + nblk_W), dim3(256), 0, stream>>>(
      x, h, sp, tp, Wx, Wh, Ws, Wt, Ap, Wp);
  lstm_gemm<<<dim3(2048), dim3(256), 0, stream>>>(Ap, Wp, bh, c, out);
}

// Round 4
// 232.495 us; speedup vs baseline: 1.1328x; 1.1328x over previous
//
#include <hip/hip_runtime.h>
#include <hip/hip_bf16.h>
#include <cstdint>

// Problem constants
#define B_DIM 16384
#define DX 256
#define DH 512
#define DS 128
#define DT 128
#define KDIM 1024   // DX+DH+DS+DT
#define NDIM 2048   // 4*DH
#define HOUT 512

typedef __attribute__((ext_vector_type(8))) short short8;
typedef __attribute__((ext_vector_type(4))) float floatx4;

union bf16x8 {
  short8 v;
  __hip_bfloat16 b[8];
};

__device__ __forceinline__ float fast_sigmoid(float x) {
  return 1.f / (1.f + __expf(-x));
}
__device__ __forceinline__ float fast_tanh(float x) {
  float e = __expf(-2.f * x);
  return (1.f - e) / (1.f + e);
}

// ===========================================================================
// Chunk-flat packed operands with BAKED-IN XOR bank swizzle.
//   A tile (mb,kb) = 128 rows x 64 k = 16 chunks of 512 bf16 (1KB).
//   chunk t16 = s*8 + c  (s = 32-k panel, c = 16-row group), lane i (0..63):
//     row = c*16 + i/4, kq_lin = i&3, kq_src = kq_lin ^ ((row>>1)&3)
//     holds A[mb*128+row][kb*64 + s*32 + kq_src*8 .. +7]
//   flat = ((mb*16+kb)*16 + t16)*512 + i*8
//   => GEMM stages with contiguous per-lane addrs (GLD dest = linear LDS
//      [s][row][kq_lin][8]); fragment read at kq_lin = q ^ ((row>>1)&3)
//      spreads 64 lanes over all 32 banks (2-way = free). Verified r2/r3:
//      conflicts = 0; verified r0: layout/epilogue correct.
// W identical over packed cols: pcol = c*16+i/4 within 128-col tile,
//   pcol <-> orig col = g*512 + nblk*32 + wn*16 + hl  (pcol = wn*64+g*16+hl)
//   (g: 0=i,1=f,2=o,3=c~) -> gate g = wave col-frag index -> register epilogue.
// ===========================================================================

__global__ __launch_bounds__(256) void pack_AW(
    const float* __restrict__ x, const float* __restrict__ h,
    const float* __restrict__ sp_, const float* __restrict__ tp_,
    const float* __restrict__ Wx, const float* __restrict__ Wh,
    const float* __restrict__ Ws, const float* __restrict__ Wt,
    __hip_bfloat16* __restrict__ Ap, __hip_bfloat16* __restrict__ Wp) {
  const int NA = B_DIM * KDIM / 8 / 256;   // 8192 A-blocks
  const int bid = blockIdx.x;
  if (bid < NA) {
    // ---- pack A ----
    int tid = bid * 256 + threadIdx.x;     // 0 .. B_DIM*KDIM/8-1
    int i = tid & 63;
    int t16 = (tid >> 6) & 15;
    int tile = tid >> 10;                  // mb*16 + kb
    int kb = tile & 15, mb = tile >> 4;
    int s = t16 >> 3, c = t16 & 7;
    int row = c * 16 + (i >> 2);
    int kq = (i & 3) ^ ((row >> 1) & 3);   // baked swizzle
    int b = mb * 128 + row;
    int k = kb * 64 + s * 32 + kq * 8;
    const float* p;
    if (k < 768) {
      p = (k < 256) ? (x + (size_t)b * DX + k) : (h + (size_t)b * DH + (k - 256));
    } else {
      p = (k < 896) ? (sp_ + (size_t)b * DS + (k - 768))
                    : (tp_ + (size_t)b * DT + (k - 896));
    }
    floatx4 v0 = *(const floatx4*)p;
    floatx4 v1 = *(const floatx4*)(p + 4);
    bf16x8 o;
#pragma unroll
    for (int j = 0; j < 4; ++j) {
      o.b[j]     = __float2bfloat16(v0[j]);
      o.b[4 + j] = __float2bfloat16(v1[j]);
    }
    *(short8*)(Ap + (size_t)tid * 8) = o.v;
  } else {
    // ---- pack W ----
    int tid = (bid - NA) * 256 + threadIdx.x;  // 0 .. NDIM*KDIM/8-1
    int i = tid & 63;
    int t16 = (tid >> 6) & 15;
    int tile = tid >> 10;                  // nblk*16 + kb
    int kb = tile & 15, nblk = tile >> 4;
    int s = t16 >> 3, c = t16 & 7;
    int pcol = c * 16 + (i >> 2);          // 0..127
    int kq = (i & 3) ^ ((pcol >> 1) & 3);  // baked swizzle
    int k = kb * 64 + s * 32 + kq * 8;
    int wn = pcol >> 6, g = (pcol >> 4) & 3, hl = pcol & 15;
    int col = g * 512 + nblk * 32 + wn * 16 + hl;
    const float* src; int kl;
    if (k < 256)      { src = Wx; kl = k; }
    else if (k < 768) { src = Wh; kl = k - 256; }
    else if (k < 896) { src = Ws; kl = k - 768; }
    else              { src = Wt; kl = k - 896; }
    bf16x8 o;
#pragma unroll
    for (int r = 0; r < 8; ++r)
      o.b[r] = __float2bfloat16(src[(size_t)(kl + r) * NDIM + col]);
    *(short8*)(Wp + (size_t)tid * 8) = o.v;
  }
}

// ---------------------------------------------------------------------------
// Round-0 structure with BK=64: 128x128 tile, 2x2 waves, 4x4 MFMA acc/wave,
// 256 threads. Per iter: 8 wave-level GLDs (16KB A + 16KB B, contiguous),
// __syncthreads, 2x{8 ds_read_b128 + 16 MFMA}, __syncthreads.
// 16 barrier-drains total (vs 32 at BK=32), conflict-free frag reads.
// ---------------------------------------------------------------------------
#define GLD(src, dst)                                              \
  __builtin_amdgcn_global_load_lds(                                \
      (const __attribute__((address_space(1))) void*)(src),        \
      (__attribute__((address_space(3))) void*)(dst), 16, 0, 0)

__global__ __launch_bounds__(256, 3) void lstm_gemm(
    const __hip_bfloat16* __restrict__ Ap, const __hip_bfloat16* __restrict__ Wp,
    const float* __restrict__ bh, const float* __restrict__ c_in,
    float* __restrict__ out) {
  __shared__ unsigned short As[8192];  // 16 KB: [s:2][row:128][kq:4][8]
  __shared__ unsigned short Bs[8192];  // 16 KB

  const int tid = threadIdx.x;
  const int lane = tid & 63;
  const int wid = tid >> 6;      // 0..3
  const int wm = wid & 1;        // row half (64 rows)
  const int wn = wid >> 1;       // col half (64 packed cols)
  const int q = lane >> 4;
  const int fr = lane & 15;

  // XCD-aware bijective swizzle (2048 blocks, 2048%8==0): contiguous wg band
  // per XCD -> A-panels and the whole 4MB W shared within one XCD's L2.
  const int bid = blockIdx.x;
  const int wg = (bid & 7) * 256 + (bid >> 3);
  const int mb = wg >> 4;        // 0..127
  const int nblk = wg & 15;      // 0..15
  const int m0 = mb * 128;

  // Fragment read offsets (ushort idx within a 32-k panel), XOR-swizzled.
  int aOff[4], bOff[4];
#pragma unroll
  for (int m = 0; m < 4; ++m) {
    int row = wm * 64 + m * 16 + fr;
    aOff[m] = row * 32 + (q ^ ((row >> 1) & 3)) * 8;
  }
#pragma unroll
  for (int n = 0; n < 4; ++n) {
    int colc = wn * 64 + n * 16 + fr;
    bOff[n] = colc * 32 + (q ^ ((colc >> 1) & 3)) * 8;
  }

  floatx4 acc[4][4];
#pragma unroll
  for (int i = 0; i < 4; ++i)
#pragma unroll
    for (int j = 0; j < 4; ++j) acc[i][j] = (floatx4)0.f;

  const __hip_bfloat16* aTile = Ap + (size_t)(mb * 16) * 8192 + lane * 8;
  const __hip_bfloat16* bTile = Wp + (size_t)(nblk * 16) * 8192 + lane * 8;

  for (int kb = 0; kb < 16; ++kb) {
    const __hip_bfloat16* ap = aTile + (size_t)kb * 8192;
    const __hip_bfloat16* bp = bTile + (size_t)kb * 8192;
#pragma unroll
    for (int j = 0; j < 4; ++j) {
      const int chunk = wid * 4 + j;      // wave-uniform, 0..15
      GLD(ap + chunk * 512, &As[chunk * 512]);
      GLD(bp + chunk * 512, &Bs[chunk * 512]);
    }
    __syncthreads();

#pragma unroll
    for (int s = 0; s < 2; ++s) {
      const int sb = s * 4096;
      short8 af[4], bf[4];
#pragma unroll
      for (int i = 0; i < 4; ++i) af[i] = *(const short8*)&As[sb + aOff[i]];
#pragma unroll
      for (int i = 0; i < 4; ++i) bf[i] = *(const short8*)&Bs[sb + bOff[i]];
#pragma unroll
      for (int mi = 0; mi < 4; ++mi)
#pragma unroll
        for (int ni = 0; ni < 4; ++ni)
          acc[mi][ni] = __builtin_amdgcn_mfma_f32_16x16x32_bf16(
              af[mi], bf[ni], acc[mi][ni], 0, 0, 0);
    }
    __syncthreads();
  }

  // ---- In-register epilogue ----
  // acc[mi][g]: rows m0 + wm*64 + mi*16 + q*4 + r, gate g of hidden hh.
  const int hh = nblk * 32 + wn * 16 + fr;
  float bias[4];
#pragma unroll
  for (int g = 0; g < 4; ++g) bias[g] = bh[g * 512 + hh];

#pragma unroll
  for (int mi = 0; mi < 4; ++mi) {
#pragma unroll
    for (int r = 0; r < 4; ++r) {
      const size_t grow = (size_t)(m0 + wm * 64 + mi * 16 + q * 4 + r);
      const float pi = acc[mi][0][r] + bias[0];
      const float pf = acc[mi][1][r] + bias[1];
      const float po = acc[mi][2][r] + bias[2];
      const float pc = acc[mi][3][r] + bias[3];
      const float ig = fast_sigmoid(pi);
      const float fg = fast_sigmoid(pf);
      const float og = fast_sigmoid(po);
      const float cg = fast_tanh(pc);
      const float cc = fg * c_in[grow * HOUT + hh] + ig * cg;
      out[grow * HOUT + hh] = fast_tanh(og * cc);  // faithful: tanh(o*c_new)
      out[(size_t)B_DIM * HOUT + grow * HOUT + hh] = cc;
    }
  }
}

// ---------------------------------------------------------------------------
extern "C" void kernel_launch(void* const* d_in, const int* in_sizes, int n_in,
                              void* d_out, int out_size, void* d_ws, size_t ws_size,
                              hipStream_t stream) {
  const float* x  = (const float*)d_in[0];
  const float* h  = (const float*)d_in[1];
  const float* c  = (const float*)d_in[2];
  const float* sp = (const float*)d_in[3];
  const float* tp = (const float*)d_in[4];
  const float* Wx = (const float*)d_in[5];
  const float* Wh = (const float*)d_in[6];
  const float* bh = (const float*)d_in[7];
  const float* Ws = (const float*)d_in[8];
  const float* Wt = (const float*)d_in[9];
  float* out = (float*)d_out;

  __hip_bfloat16* Ap = (__hip_bfloat16*)d_ws;                                     // 32 MB
  __hip_bfloat16* Wp = (__hip_bfloat16*)((char*)d_ws + (size_t)B_DIM * KDIM * 2); // 4 MB

  const int nblk_A = B_DIM * KDIM / 8 / 256;   // 8192
  const int nblk_W = NDIM * KDIM / 8 / 256;    // 1024
  pack_AW<<<dim3(nblk_A + nblk_W), dim3(256), 0, stream>>>(
      x, h, sp, tp, Wx, Wh, Ws, Wt, Ap, Wp);
  lstm_gemm<<<dim3(2048), dim3(256), 0, stream>>>(Ap, Wp, bh, c, out);
}